// Round 6
// baseline (133.152 us; speedup 1.0000x reference)
//
#include <hip/hip_runtime.h>
#include <hip/hip_bf16.h>
#include <cstdint>
#include <cstddef>

typedef __attribute__((ext_vector_type(8))) short short8;
typedef __attribute__((ext_vector_type(4))) short short4v;
typedef __attribute__((ext_vector_type(4))) float f32x4;
typedef __attribute__((ext_vector_type(16))) float f32x16;

#define HH 12
#define DD 64
#define NN 2048
#define CC 768
// 0.125 (HEAD_DIM^-0.5) * log2(e): lets attn use exp2 directly.
#define QSCALE 0.18033688011112042f
#define PART_STRIDE 8448   // 128*64 pv + 128 l1 + 128 mc

__device__ __forceinline__ float bf2f(short s) {
  union { uint32_t u; float f; } v;
  v.u = ((uint32_t)(uint16_t)s) << 16;
  return v.f;
}
__device__ __forceinline__ short f2bf(float f) {
  union { float f; uint32_t u; } v; v.f = f;
  uint32_t r = v.u + 0x7FFFu + ((v.u >> 16) & 1u);
  return (short)(r >> 16);
}
// packed f32x2 -> bf16x2 (low = a, high = b) in one instruction
__device__ __forceinline__ uint32_t cvtpk(float a, float b) {
  uint32_t r;
  asm("v_cvt_pk_bf16_f32 %0, %1, %2" : "=v"(r) : "v"(a), "v"(b));
  return r;
}

// ---------------------------------------------------------------------------
// Normalizer: fp32 -> bf16 for x, w_qkv, w_out.
// ---------------------------------------------------------------------------
__global__ __launch_bounds__(256)
void norm_k(const float* __restrict__ s0, const float* __restrict__ s1,
            const float* __restrict__ s2,
            short* __restrict__ d0, short* __restrict__ d1,
            short* __restrict__ d2)
{
  const int bid = blockIdx.x;
  const float* src; short* dst; int base;
  if (bid < 1536)      { src = s0; dst = d0; base = bid; }
  else if (bid < 2400) { src = s1; dst = d1; base = bid - 1536; }
  else                 { src = s2; dst = d2; base = bid - 2400; }
  const int idx = (base * 256 + (int)threadIdx.x) * 8;
  const float* sf = src + idx;
  f32x4 a = *(const f32x4*)sf;
  f32x4 b = *(const f32x4*)(sf + 4);
  short8 o;
  o[0] = f2bf(a[0]); o[1] = f2bf(a[1]); o[2] = f2bf(a[2]); o[3] = f2bf(a[3]);
  o[4] = f2bf(b[0]); o[5] = f2bf(b[1]); o[6] = f2bf(b[2]); o[7] = f2bf(b[3]);
  *(short8*)(dst + idx) = o;
}

// ---------------------------------------------------------------------------
// GEMM: C[m,f] = sum_c A[m,c] * W[f,c]   (A: [4096,768], W: [F,768], bf16)
// MODE 0: F=2304 -> Q (x QSCALE) [b,h,n,d], K [b,h,n,d], V^T [b,h,d,n]
// MODE 1: F=768 -> Of[m*768+f] = C + bias[f]  (fp32 out)
// ---------------------------------------------------------------------------
template <int MODE>
__global__ __launch_bounds__(256, 2)
void gemm_k(const short* __restrict__ A, const short* __restrict__ W,
            const float* __restrict__ bias,
            short* __restrict__ O0, short* __restrict__ O1, short* __restrict__ O2,
            float* __restrict__ Of)
{
  __shared__ __align__(16) short lA[128 * 64];
  __shared__ __align__(16) short lB[128 * 64];
  const int tid = threadIdx.x;
  const int w = tid >> 6, l = tid & 63;
  const int lq = l & 15, lh = l >> 4;
  const int m0 = blockIdx.y * 128;
  const int f0 = blockIdx.x * 128;
  const int seg = tid & 7;
  const int rbase = tid >> 3;

  f32x4 acc[4][4] = {};

  for (int kb = 0; kb < CC; kb += 64) {
    __syncthreads();
#pragma unroll
    for (int j = 0; j < 4; ++j) {
      const int row = j * 32 + rbase;
      const int dst = row * 128 + ((seg * 16) ^ ((row & 7) << 4));
      *(short8*)((char*)lA + dst) =
          *(const short8*)(A + (size_t)(m0 + row) * CC + kb + seg * 8);
      *(short8*)((char*)lB + dst) =
          *(const short8*)(W + (size_t)(f0 + row) * CC + kb + seg * 8);
    }
    __syncthreads();
    const int wr = (w >> 1) * 64, wc = (w & 1) * 64;
#pragma unroll
    for (int c = 0; c < 2; ++c) {
      short8 af[4], bfr[4];
#pragma unroll
      for (int i = 0; i < 4; ++i) {
        const int rowA = wr + i * 16 + lq;
        af[i] = *(const short8*)((char*)lA + rowA * 128 +
                                 ((c * 64 + lh * 16) ^ ((rowA & 7) << 4)));
        const int rowB = wc + i * 16 + lq;
        bfr[i] = *(const short8*)((char*)lB + rowB * 128 +
                                  ((c * 64 + lh * 16) ^ ((rowB & 7) << 4)));
      }
#pragma unroll
      for (int mi = 0; mi < 4; ++mi)
#pragma unroll
        for (int ni = 0; ni < 4; ++ni)
          acc[mi][ni] = __builtin_amdgcn_mfma_f32_16x16x32_bf16(
              af[mi], bfr[ni], acc[mi][ni], 0, 0, 0);
    }
  }

  const int wr = (w >> 1) * 64, wc = (w & 1) * 64;
#pragma unroll
  for (int ni = 0; ni < 4; ++ni) {
    const int fb = f0 + wc + ni * 16;
    if (MODE == 0) {
      const int which = fb / CC;          // uniform per fragment
      const int hd = fb - which * CC;
      const int h = hd >> 6;              // uniform
      const int d = (hd & 63) + lq;
#pragma unroll
      for (int mi = 0; mi < 4; ++mi) {
        const int mb = m0 + wr + mi * 16 + 4 * lh;
        const int b = mb >> 11;
        const int n = mb & 2047;
        if (which == 0) {
#pragma unroll
          for (int r = 0; r < 4; ++r)
            O0[(((size_t)(b * HH + h) * NN) + n + r) * DD + d] =
                f2bf(acc[mi][ni][r] * QSCALE);
        } else if (which == 1) {
#pragma unroll
          for (int r = 0; r < 4; ++r)
            O1[(((size_t)(b * HH + h) * NN) + n + r) * DD + d] =
                f2bf(acc[mi][ni][r]);
        } else {
          short4v pk;
#pragma unroll
          for (int r = 0; r < 4; ++r) pk[r] = f2bf(acc[mi][ni][r]);
          *(short4v*)(O2 + ((size_t)(b * HH + h) * DD + d) * NN + n) = pk;
        }
      }
    } else {
      const float bv = bias[fb + lq];
#pragma unroll
      for (int mi = 0; mi < 4; ++mi) {
        const int mb = m0 + wr + mi * 16 + 4 * lh;
#pragma unroll
        for (int r = 0; r < 4; ++r)
          Of[(size_t)(mb + r) * CC + fb + lq] = acc[mi][ni][r] + bv;
      }
    }
  }
}

// ---------------------------------------------------------------------------
// colsumV[bh,d] = sum_n V[bh,n,d]  (from V^T [bh,d,n])
// ---------------------------------------------------------------------------
__global__ __launch_bounds__(256)
void colsum_k(const short* __restrict__ VT, float* __restrict__ cs)
{
  const int bh = blockIdx.x, t = threadIdx.x;
  const int d = t >> 2, part = t & 3;
  const short* p = VT + ((size_t)bh * DD + d) * NN + part * 512;
  float s = 0.f;
  for (int i = 0; i < 512; i += 8) {
    short8 v = *(const short8*)(p + i);
#pragma unroll
    for (int e = 0; e < 8; ++e) s += bf2f(v[e]);
  }
  s += __shfl_xor(s, 1);
  s += __shfl_xor(s, 2);
  if (part == 0) cs[bh * DD + d] = s;
}

// ---------------------------------------------------------------------------
// Attention with 32x32x16 MFMA.  Per wave: 32 queries (swapped QK^T: lane owns
// q = lane&31).  P->A-frag redistribution via v_permlane32_swap_b32 (VALU),
// no bpermute, no LDS round-trip.  Linearized 2nd softmax:
//   out = (csV*l1 + P1) / (2048*l1 + s1),  s1 = l1 - 0.5*mc.
// NSPLIT>1: fp32 partial dump (pv, l1, mc) -> combine_k.
// ---------------------------------------------------------------------------
template <int NSPLIT>
__global__ __launch_bounds__(256, 3)
void attn_k(const short* __restrict__ Qb, const short* __restrict__ Kb,
            const short* __restrict__ VT, const float* __restrict__ cs,
            short* __restrict__ AO, float* __restrict__ part)
{
  __shared__ __align__(16) short lK[64 * 64];   // [key][d]   XOR-swizzled rows
  __shared__ __align__(16) short lV[64 * 64];   // [d][key]   XOR-swizzled rows
  const int tid = threadIdx.x;
  const int w = tid >> 6, l = tid & 63;
  const int lq = l & 31;          // q lane (QK^T C-col) and d lane (PV C-col)
  const int hi = l >> 5;
  const int bx = blockIdx.x;
  const int bh = bx / (16 * NSPLIT);
  const int rem = bx - bh * (16 * NSPLIT);
  const int qblk = rem / NSPLIT;
  const int ks = rem - qblk * NSPLIT;

  const short* Qh = Qb + (size_t)bh * NN * DD;
  const short* Kh = Kb + (size_t)bh * NN * DD;
  const short* Vh = VT + (size_t)bh * DD * NN;

  const int qw = qblk * 128 + w * 32;
  const int qg = qw + lq;

  // B-frag of Q: rows d = c*16 + hi*8 + 0..7, col q = lq
  short8 qf[4];
#pragma unroll
  for (int c = 0; c < 4; ++c)
    qf[c] = *(const short8*)(Qh + (size_t)qg * DD + c * 16 + hi * 8);

  f32x16 pv[2] = {};
  float l1 = 0.f, mc = 0.f;

  const int seg = tid & 7, rbase = tid >> 3;

  const int KSPAN = NN / NSPLIT;
  const int kb0 = ks * KSPAN;
  for (int t = 0; t < KSPAN; t += 64) {
    const int kb = kb0 + t;
    __syncthreads();
#pragma unroll
    for (int j = 0; j < 2; ++j) {
      const int row = j * 32 + rbase;
      const int dst = row * 128 + ((seg * 16) ^ ((row & 7) << 4));
      *(short8*)((char*)lK + dst) =
          *(const short8*)(Kh + (size_t)(kb + row) * DD + seg * 8);
      *(short8*)((char*)lV + dst) =
          *(const short8*)(Vh + (size_t)row * NN + kb + seg * 8);
    }
    __syncthreads();

    // QK^T: sacc[kg] = S[key = kb + kg*32 + crow, q = qg] * log2e
    // crow = (reg&3) + 8*(reg>>2) + 4*hi
    f32x16 sacc[2] = {};
#pragma unroll
    for (int kg = 0; kg < 2; ++kg) {
      const int rowK = kg * 32 + lq;
#pragma unroll
      for (int c = 0; c < 4; ++c) {
        short8 kf = *(const short8*)((char*)lK + rowK * 128 +
                                     ((c * 32 + hi * 16) ^ ((rowK & 7) << 4)));
        sacc[kg] = __builtin_amdgcn_mfma_f32_32x32x16_bf16(kf, qf[c], sacc[kg], 0, 0, 0);
      }
    }

    // elementwise: e = exp2(s); mask hoisted to rare wave-uniform tiles
    uint32_t dwv[2][8];
    const int u = (qw - kb) & 511;
    if (u < 64 || u > 480) {
      const int delta = (qg - kb) & 511;
      int mreg = -1;
      if (delta < 64 && (((delta >> 2) & 1) == hi))
        mreg = (delta >> 5) * 16 + (delta & 3) + (((delta & 31) >> 3) << 2);
#pragma unroll
      for (int kg = 0; kg < 2; ++kg) {
        float uv[16];
#pragma unroll
        for (int r = 0; r < 16; ++r) {
          float e = __builtin_exp2f(sacc[kg][r]);
          l1 += e;
          const bool m = (kg * 16 + r) == mreg;
          mc += m ? e : 0.f;
          uv[r] = m ? 0.5f * e : e;
        }
#pragma unroll
        for (int j2 = 0; j2 < 8; ++j2)
          dwv[kg][j2] = cvtpk(uv[2 * j2], uv[2 * j2 + 1]);
      }
    } else {
#pragma unroll
      for (int kg = 0; kg < 2; ++kg) {
        float uv[16];
#pragma unroll
        for (int r = 0; r < 16; ++r) {
          const float e = __builtin_exp2f(sacc[kg][r]);
          l1 += e;
          uv[r] = e;
        }
#pragma unroll
        for (int j2 = 0; j2 < 8; ++j2)
          dwv[kg][j2] = cvtpk(uv[2 * j2], uv[2 * j2 + 1]);
      }
    }

    // Build PV A-frags (P[q][k], row=q=lq, cols k = ch*16 + hi*8 + 0..7)
    // via permlane32_swap: r0 = [a.lo32|b.lo32], r1 = [a.hi32|b.hi32].
    short8 pa[4];
#pragma unroll
    for (int kg = 0; kg < 2; ++kg) {
#pragma unroll
      for (int half = 0; half < 2; ++half) {
        uint32_t a0 = dwv[kg][4 * half + 0], a1 = dwv[kg][4 * half + 1];
        uint32_t a2 = dwv[kg][4 * half + 2], a3 = dwv[kg][4 * half + 3];
        asm("v_permlane32_swap_b32 %0, %1" : "+v"(a0), "+v"(a2));
        asm("v_permlane32_swap_b32 %0, %1" : "+v"(a1), "+v"(a3));
        union { uint32_t u4[4]; short8 s; } pk;
        pk.u4[0] = a0; pk.u4[1] = a1; pk.u4[2] = a2; pk.u4[3] = a3;
        pa[kg * 2 + half] = pk.s;
      }
    }

    // PV: pv[dg][reg] = O[q = crow, d = dg*32 + lq]
#pragma unroll
    for (int ch = 0; ch < 4; ++ch) {
#pragma unroll
      for (int dg = 0; dg < 2; ++dg) {
        const int rowV = dg * 32 + lq;
        short8 vf = *(const short8*)((char*)lV + rowV * 128 +
                                     ((ch * 32 + hi * 16) ^ ((rowV & 7) << 4)));
        pv[dg] = __builtin_amdgcn_mfma_f32_32x32x16_bf16(pa[ch], vf, pv[dg], 0, 0, 0);
      }
    }
  }

  // full-tile-range l1, mc for q = qw + lq (keys split across lane halves)
  l1 += __shfl_xor(l1, 32);
  mc += __shfl_xor(mc, 32);

  if (NSPLIT > 1) {
    float* pb = part + (size_t)bx * PART_STRIDE;
#pragma unroll
    for (int dg = 0; dg < 2; ++dg)
#pragma unroll
      for (int r = 0; r < 16; ++r) {
        const int qlocal = w * 32 + (r & 3) + 8 * (r >> 2) + 4 * hi;
        pb[qlocal * 64 + dg * 32 + lq] = pv[dg][r];
      }
    if (hi == 0) {
      pb[8192 + w * 32 + lq] = l1;
      pb[8320 + w * 32 + lq] = mc;
    }
  } else {
    const int b = bh / HH, h = bh - b * HH;
    const float s1 = l1 - 0.5f * mc;
#pragma unroll
    for (int r = 0; r < 16; ++r) {
      const int qrow = (r & 3) + 8 * (r >> 2) + 4 * hi;
      const float l1r = __shfl(l1, qrow);
      const float s1r = __shfl(s1, qrow);
      const float rden = 1.f / (2048.f * l1r + s1r);
      const int n = qw + qrow;
#pragma unroll
      for (int dg = 0; dg < 2; ++dg) {
        const int d = dg * 32 + lq;
        const float csv = cs[bh * DD + d];
        AO[((size_t)(b * NN + n)) * CC + h * DD + d] =
            f2bf((csv * l1r + pv[dg][r]) * rden);
      }
    }
  }
}

// ---------------------------------------------------------------------------
// Combine split-K partials -> AO (bf16).  Grid: 24*16 blocks, 256 thr.
// ---------------------------------------------------------------------------
template <int NSPLIT>
__global__ __launch_bounds__(256)
void combine_k(const float* __restrict__ part, const float* __restrict__ cs,
               short* __restrict__ AO)
{
  const int bh = blockIdx.x >> 4;
  const int qblk = blockIdx.x & 15;
  const int t = threadIdx.x;
  const int q = t >> 1;
  const int d0 = (t & 1) * 32;
  const float* rec = part + (size_t)((bh * 16 + qblk) * NSPLIT) * PART_STRIDE;
  float l1 = 0.f, mcv = 0.f;
#pragma unroll
  for (int k = 0; k < NSPLIT; ++k) {
    l1  += rec[k * PART_STRIDE + 8192 + q];
    mcv += rec[k * PART_STRIDE + 8320 + q];
  }
  const float s1 = l1 - 0.5f * mcv;
  const float rden = 1.f / (2048.f * l1 + s1);
  const int b = bh / HH, h = bh - b * HH;
  const int n = qblk * 128 + q;
  short* dst = AO + ((size_t)(b * NN + n)) * CC + h * DD + d0;
#pragma unroll
  for (int i = 0; i < 32; i += 4) {
    f32x4 a = {};
#pragma unroll
    for (int k = 0; k < NSPLIT; ++k)
      a += *(const f32x4*)(rec + k * PART_STRIDE + q * 64 + d0 + i);
    f32x4 cv = *(const f32x4*)(cs + bh * DD + d0 + i);
    short4v o;
#pragma unroll
    for (int e = 0; e < 4; ++e) o[e] = f2bf((cv[e] * l1 + a[e]) * rden);
    *(short4v*)(dst + i) = o;
  }
}

// ---------------------------------------------------------------------------
extern "C" void kernel_launch(void* const* d_in, const int* in_sizes, int n_in,
                              void* d_out, int out_size, void* d_ws, size_t ws_size,
                              hipStream_t stream)
{
  (void)in_sizes; (void)n_in; (void)out_size;
  float* out = (float*)d_out;

  const size_t HD = (size_t)2 * HH * NN * DD;   // 3,145,728 elements
  const size_t NX = 3145728, NW = 1769472, NO = 589824;
  const size_t base_need = (4 * HD + NX + NW + NO) * sizeof(short)
                         + (size_t)2 * HH * DD * sizeof(float) + 64;
  const size_t part4 = (size_t)24 * 16 * 4 * PART_STRIDE * sizeof(float);
  const size_t part2 = (size_t)24 * 16 * 2 * PART_STRIDE * sizeof(float);
  if (ws_size < base_need) return;  // diagnostic: zero output

  short* Qb = (short*)d_ws;
  short* Kb = Qb + HD;
  short* VT = Kb + HD;
  short* AO = VT + HD;
  float* cs = (float*)(AO + HD);
  short* xb  = (short*)(cs + 2 * HH * DD);
  short* wqb = xb + NX;
  short* wob = wqb + NW;
  float* part = (float*)(wob + NO);

  dim3 blk(256);
  norm_k<<<dim3(2688), blk, 0, stream>>>((const float*)d_in[0],
                                         (const float*)d_in[1],
                                         (const float*)d_in[2],
                                         xb, wqb, wob);
  gemm_k<0><<<dim3(2304 / 128, 4096 / 128), blk, 0, stream>>>(
      xb, wqb, nullptr, Qb, Kb, VT, nullptr);
  colsum_k<<<dim3(2 * HH), blk, 0, stream>>>(VT, cs);
  if (ws_size >= base_need + part4) {
    attn_k<4><<<dim3(24 * 16 * 4), blk, 0, stream>>>(Qb, Kb, VT, cs, AO, part);
    combine_k<4><<<dim3(24 * 16), blk, 0, stream>>>(part, cs, AO);
  } else if (ws_size >= base_need + part2) {
    attn_k<2><<<dim3(24 * 16 * 2), blk, 0, stream>>>(Qb, Kb, VT, cs, AO, part);
    combine_k<2><<<dim3(24 * 16), blk, 0, stream>>>(part, cs, AO);
  } else {
    attn_k<1><<<dim3(24 * 16), blk, 0, stream>>>(Qb, Kb, VT, cs, AO, nullptr);
  }
  gemm_k<1><<<dim3(CC / 128, 4096 / 128), blk, 0, stream>>>(
      AO, wob, (const float*)d_in[3], nullptr, nullptr, nullptr, out);
}

// Round 7
// 126.989 us; speedup vs baseline: 1.0485x; 1.0485x over previous
//
#include <hip/hip_runtime.h>
#include <hip/hip_bf16.h>
#include <cstdint>
#include <cstddef>

typedef __attribute__((ext_vector_type(8))) short short8;
typedef __attribute__((ext_vector_type(4))) short short4v;
typedef __attribute__((ext_vector_type(4))) float f32x4;
typedef __attribute__((ext_vector_type(16))) float f32x16;

#define HH 12
#define DD 64
#define NN 2048
#define CC 768
// 0.125 (HEAD_DIM^-0.5) * log2(e): lets attn use exp2 directly.
#define QSCALE 0.18033688011112042f

__device__ __forceinline__ float bf2f(short s) {
  union { uint32_t u; float f; } v;
  v.u = ((uint32_t)(uint16_t)s) << 16;
  return v.f;
}
__device__ __forceinline__ short f2bf(float f) {
  union { float f; uint32_t u; } v; v.f = f;
  uint32_t r = v.u + 0x7FFFu + ((v.u >> 16) & 1u);
  return (short)(r >> 16);
}
// packed f32x2 -> bf16x2 (low = a, high = b) in one instruction
__device__ __forceinline__ uint32_t cvtpk(float a, float b) {
  uint32_t r;
  asm("v_cvt_pk_bf16_f32 %0, %1, %2" : "=v"(r) : "v"(a), "v"(b));
  return r;
}

// ---------------------------------------------------------------------------
// Normalizer: fp32 -> bf16 for x, w_qkv, w_out.
// ---------------------------------------------------------------------------
__global__ __launch_bounds__(256)
void norm_k(const float* __restrict__ s0, const float* __restrict__ s1,
            const float* __restrict__ s2,
            short* __restrict__ d0, short* __restrict__ d1,
            short* __restrict__ d2)
{
  const int bid = blockIdx.x;
  const float* src; short* dst; int base;
  if (bid < 1536)      { src = s0; dst = d0; base = bid; }
  else if (bid < 2400) { src = s1; dst = d1; base = bid - 1536; }
  else                 { src = s2; dst = d2; base = bid - 2400; }
  const int idx = (base * 256 + (int)threadIdx.x) * 8;
  const float* sf = src + idx;
  f32x4 a = *(const f32x4*)sf;
  f32x4 b = *(const f32x4*)(sf + 4);
  short8 o;
  o[0] = f2bf(a[0]); o[1] = f2bf(a[1]); o[2] = f2bf(a[2]); o[3] = f2bf(a[3]);
  o[4] = f2bf(b[0]); o[5] = f2bf(b[1]); o[6] = f2bf(b[2]); o[7] = f2bf(b[3]);
  *(short8*)(dst + idx) = o;
}

// ---------------------------------------------------------------------------
// GEMM: C[m,f] = sum_c A[m,c] * W[f,c]   (A: [4096,768], W: [F,768], bf16)
// MODE 0: F=2304 -> Q (x QSCALE) [b,h,n,d], K [b,h,n,d], V^T [b,h,d,n]
// MODE 1: F=768 -> Of[m*768+f] = C + bias[f]  (fp32 out)
// ---------------------------------------------------------------------------
template <int MODE>
__global__ __launch_bounds__(256, 2)
void gemm_k(const short* __restrict__ A, const short* __restrict__ W,
            const float* __restrict__ bias,
            short* __restrict__ O0, short* __restrict__ O1, short* __restrict__ O2,
            float* __restrict__ Of)
{
  __shared__ __align__(16) short lA[128 * 64];
  __shared__ __align__(16) short lB[128 * 64];
  const int tid = threadIdx.x;
  const int w = tid >> 6, l = tid & 63;
  const int lq = l & 15, lh = l >> 4;
  const int m0 = blockIdx.y * 128;
  const int f0 = blockIdx.x * 128;
  const int seg = tid & 7;
  const int rbase = tid >> 3;

  f32x4 acc[4][4] = {};

  for (int kb = 0; kb < CC; kb += 64) {
    __syncthreads();
#pragma unroll
    for (int j = 0; j < 4; ++j) {
      const int row = j * 32 + rbase;
      const int dst = row * 128 + ((seg * 16) ^ ((row & 7) << 4));
      *(short8*)((char*)lA + dst) =
          *(const short8*)(A + (size_t)(m0 + row) * CC + kb + seg * 8);
      *(short8*)((char*)lB + dst) =
          *(const short8*)(W + (size_t)(f0 + row) * CC + kb + seg * 8);
    }
    __syncthreads();
    const int wr = (w >> 1) * 64, wc = (w & 1) * 64;
#pragma unroll
    for (int c = 0; c < 2; ++c) {
      short8 af[4], bfr[4];
#pragma unroll
      for (int i = 0; i < 4; ++i) {
        const int rowA = wr + i * 16 + lq;
        af[i] = *(const short8*)((char*)lA + rowA * 128 +
                                 ((c * 64 + lh * 16) ^ ((rowA & 7) << 4)));
        const int rowB = wc + i * 16 + lq;
        bfr[i] = *(const short8*)((char*)lB + rowB * 128 +
                                  ((c * 64 + lh * 16) ^ ((rowB & 7) << 4)));
      }
#pragma unroll
      for (int mi = 0; mi < 4; ++mi)
#pragma unroll
        for (int ni = 0; ni < 4; ++ni)
          acc[mi][ni] = __builtin_amdgcn_mfma_f32_16x16x32_bf16(
              af[mi], bfr[ni], acc[mi][ni], 0, 0, 0);
    }
  }

  const int wr = (w >> 1) * 64, wc = (w & 1) * 64;
#pragma unroll
  for (int ni = 0; ni < 4; ++ni) {
    const int fb = f0 + wc + ni * 16;
    if (MODE == 0) {
      const int which = fb / CC;          // uniform per fragment
      const int hd = fb - which * CC;
      const int h = hd >> 6;              // uniform
      const int d = (hd & 63) + lq;
#pragma unroll
      for (int mi = 0; mi < 4; ++mi) {
        const int mb = m0 + wr + mi * 16 + 4 * lh;
        const int b = mb >> 11;
        const int n = mb & 2047;
        if (which == 0) {
#pragma unroll
          for (int r = 0; r < 4; ++r)
            O0[(((size_t)(b * HH + h) * NN) + n + r) * DD + d] =
                f2bf(acc[mi][ni][r] * QSCALE);
        } else if (which == 1) {
#pragma unroll
          for (int r = 0; r < 4; ++r)
            O1[(((size_t)(b * HH + h) * NN) + n + r) * DD + d] =
                f2bf(acc[mi][ni][r]);
        } else {
          short4v pk;
#pragma unroll
          for (int r = 0; r < 4; ++r) pk[r] = f2bf(acc[mi][ni][r]);
          *(short4v*)(O2 + ((size_t)(b * HH + h) * DD + d) * NN + n) = pk;
        }
      }
    } else {
      const float bv = bias[fb + lq];
#pragma unroll
      for (int mi = 0; mi < 4; ++mi) {
        const int mb = m0 + wr + mi * 16 + 4 * lh;
#pragma unroll
        for (int r = 0; r < 4; ++r)
          Of[(size_t)(mb + r) * CC + fb + lq] = acc[mi][ni][r] + bv;
      }
    }
  }
}

// ---------------------------------------------------------------------------
// colsumV[bh,d] = sum_n V[bh,n,d]  (from V^T [bh,d,n])
// ---------------------------------------------------------------------------
__global__ __launch_bounds__(256)
void colsum_k(const short* __restrict__ VT, float* __restrict__ cs)
{
  const int bh = blockIdx.x, t = threadIdx.x;
  const int d = t >> 2, part = t & 3;
  const short* p = VT + ((size_t)bh * DD + d) * NN + part * 512;
  float s = 0.f;
  for (int i = 0; i < 512; i += 8) {
    short8 v = *(const short8*)(p + i);
#pragma unroll
    for (int e = 0; e < 8; ++e) s += bf2f(v[e]);
  }
  s += __shfl_xor(s, 1);
  s += __shfl_xor(s, 2);
  if (part == 0) cs[bh * DD + d] = s;
}

// ---------------------------------------------------------------------------
// Attention, q-split (no combine): 768 blocks x 128 thr (2 waves x 32 q),
// full 2048-key sweep.  32x32x16 MFMA, swapped QK^T (lane owns q = lane&31),
// P->A-frag via v_permlane32_swap_b32.  Linearized 2nd softmax:
//   out = (csV*l1 + P1) / (2048*l1 + s1),  s1 = l1 - 0.5*mc.
// All LDS read addresses hoisted out of the K-loop (loop-invariant).
// ---------------------------------------------------------------------------
__global__ __launch_bounds__(128, 3)
void attn_k(const short* __restrict__ Qb, const short* __restrict__ Kb,
            const short* __restrict__ VT, const float* __restrict__ cs,
            short* __restrict__ AO)
{
  __shared__ __align__(16) short lK[64 * 64];   // [key][d]   XOR-swizzled rows
  __shared__ __align__(16) short lV[64 * 64];   // [d][key]   XOR-swizzled rows
  const int tid = threadIdx.x;
  const int w = tid >> 6, l = tid & 63;
  const int lq = l & 31;          // q lane (QK^T C-col) and d lane (PV C-col)
  const int hi = l >> 5;

  // XCD-aware chunked swizzle: 768 % 8 == 0, bijective.
  const int bid = (int)blockIdx.x;
  const int sbid = (bid & 7) * 96 + (bid >> 3);
  const int bh = sbid >> 5;
  const int qblk = sbid & 31;

  const short* Qh = Qb + (size_t)bh * NN * DD;
  const short* Kh = Kb + (size_t)bh * NN * DD;
  const short* Vh = VT + (size_t)bh * DD * NN;

  const int qw = qblk * 64 + w * 32;
  const int qg = qw + lq;

  // B-frag of Q: rows d = c*16 + hi*8 + 0..7, col q = lq
  short8 qf[4];
#pragma unroll
  for (int c = 0; c < 4; ++c)
    qf[c] = *(const short8*)(Qh + (size_t)qg * DD + c * 16 + hi * 8);

  f32x16 pv[2] = {};
  float l1x[4] = {};
  float mc = 0.f;

  // staging geometry (128 threads cover 64 rows x 8 seg)
  const int seg = tid & 7, rbase = tid >> 3;       // rbase in [0,16)
  int sdst[4], ksrc[4], vsrc[4];
#pragma unroll
  for (int j = 0; j < 4; ++j) {
    const int row = j * 16 + rbase;
    sdst[j] = row * 128 + ((seg * 16) ^ ((row & 7) << 4));
    ksrc[j] = row * DD + seg * 8;          // + kb*DD per tile
    vsrc[j] = row * NN + seg * 8;          // + kb per tile
  }
  // hoisted LDS read addresses (loop-invariant)
  int kaddr[8], vaddr[8];
#pragma unroll
  for (int kg = 0; kg < 2; ++kg) {
    const int rowK = kg * 32 + lq;
#pragma unroll
    for (int c = 0; c < 4; ++c)
      kaddr[kg * 4 + c] = rowK * 128 + ((c * 32 + hi * 16) ^ ((rowK & 7) << 4));
  }
#pragma unroll
  for (int dg = 0; dg < 2; ++dg) {
    const int rowV = dg * 32 + lq;
#pragma unroll
    for (int ch = 0; ch < 4; ++ch)
      vaddr[ch * 2 + dg] = rowV * 128 + ((ch * 32 + hi * 16) ^ ((rowV & 7) << 4));
  }

  for (int kb = 0; kb < NN; kb += 64) {
    __syncthreads();
#pragma unroll
    for (int j = 0; j < 4; ++j) {
      *(short8*)((char*)lK + sdst[j]) = *(const short8*)(Kh + kb * DD + ksrc[j]);
      *(short8*)((char*)lV + sdst[j]) = *(const short8*)(Vh + kb + vsrc[j]);
    }
    __syncthreads();

    // QK^T: sacc[kg] = S[key = kb + kg*32 + crow, q = qg] * log2e
    // crow = (reg&3) + 8*(reg>>2) + 4*hi
    f32x16 sacc[2] = {};
#pragma unroll
    for (int kg = 0; kg < 2; ++kg)
#pragma unroll
      for (int c = 0; c < 4; ++c) {
        short8 kf = *(const short8*)((char*)lK + kaddr[kg * 4 + c]);
        sacc[kg] = __builtin_amdgcn_mfma_f32_32x32x16_bf16(kf, qf[c], sacc[kg], 0, 0, 0);
      }

    // elementwise: e = exp2(s); mask hoisted to rare wave-uniform tiles
    uint32_t dwv[2][8];
    const int u = (qw - kb) & 511;
    if (u < 64 || u > 480) {
      const int delta = (qg - kb) & 511;
      int mreg = -1;
      if (delta < 64 && (((delta >> 2) & 1) == hi))
        mreg = (delta >> 5) * 16 + (delta & 3) + (((delta & 31) >> 3) << 2);
#pragma unroll
      for (int kg = 0; kg < 2; ++kg) {
        float uv[16];
#pragma unroll
        for (int r = 0; r < 16; ++r) {
          float e = __builtin_exp2f(sacc[kg][r]);
          l1x[r & 3] += e;
          const bool m = (kg * 16 + r) == mreg;
          mc += m ? e : 0.f;
          uv[r] = m ? 0.5f * e : e;
        }
#pragma unroll
        for (int j2 = 0; j2 < 8; ++j2)
          dwv[kg][j2] = cvtpk(uv[2 * j2], uv[2 * j2 + 1]);
      }
    } else {
#pragma unroll
      for (int kg = 0; kg < 2; ++kg) {
        float uv[16];
#pragma unroll
        for (int r = 0; r < 16; ++r) {
          const float e = __builtin_exp2f(sacc[kg][r]);
          l1x[r & 3] += e;
          uv[r] = e;
        }
#pragma unroll
        for (int j2 = 0; j2 < 8; ++j2)
          dwv[kg][j2] = cvtpk(uv[2 * j2], uv[2 * j2 + 1]);
      }
    }

    // Build PV A-frags (P[q][k], row=q=lq, cols k = ch*16 + hi*8 + 0..7)
    // via permlane32_swap: one swap pair fills two A-frag dwords.
    short8 pa[4];
#pragma unroll
    for (int kg = 0; kg < 2; ++kg)
#pragma unroll
      for (int half = 0; half < 2; ++half) {
        uint32_t a0 = dwv[kg][4 * half + 0], a1 = dwv[kg][4 * half + 1];
        uint32_t a2 = dwv[kg][4 * half + 2], a3 = dwv[kg][4 * half + 3];
        asm("v_permlane32_swap_b32 %0, %1" : "+v"(a0), "+v"(a2));
        asm("v_permlane32_swap_b32 %0, %1" : "+v"(a1), "+v"(a3));
        union { uint32_t u4[4]; short8 s; } pk;
        pk.u4[0] = a0; pk.u4[1] = a1; pk.u4[2] = a2; pk.u4[3] = a3;
        pa[kg * 2 + half] = pk.s;
      }

    // PV: pv[dg][reg] = O[q = crow, d = dg*32 + lq]
#pragma unroll
    for (int ch = 0; ch < 4; ++ch)
#pragma unroll
      for (int dg = 0; dg < 2; ++dg) {
        short8 vf = *(const short8*)((char*)lV + vaddr[ch * 2 + dg]);
        pv[dg] = __builtin_amdgcn_mfma_f32_32x32x16_bf16(pa[ch], vf, pv[dg], 0, 0, 0);
      }
  }

  // full l1, mc for q = qw + lq (keys split across lane halves)
  float l1 = (l1x[0] + l1x[1]) + (l1x[2] + l1x[3]);
  l1 += __shfl_xor(l1, 32);
  mc += __shfl_xor(mc, 32);
  const float s1 = l1 - 0.5f * mc;

  const int b = bh / HH, h = bh - b * HH;
#pragma unroll
  for (int r = 0; r < 16; ++r) {
    const int qrow = (r & 3) + 8 * (r >> 2) + 4 * hi;
    const float l1r = __shfl(l1, qrow);
    const float s1r = __shfl(s1, qrow);
    const float rden = 1.f / (2048.f * l1r + s1r);
    const int n = qw + qrow;
#pragma unroll
    for (int dg = 0; dg < 2; ++dg) {
      const int d = dg * 32 + lq;
      const float csv = cs[bh * DD + d];
      AO[((size_t)(b * NN + n)) * CC + h * DD + d] =
          f2bf((csv * l1r + pv[dg][r]) * rden);
    }
  }
}

// ---------------------------------------------------------------------------
extern "C" void kernel_launch(void* const* d_in, const int* in_sizes, int n_in,
                              void* d_out, int out_size, void* d_ws, size_t ws_size,
                              hipStream_t stream)
{
  (void)in_sizes; (void)n_in; (void)out_size;
  float* out = (float*)d_out;

  const size_t HD = (size_t)2 * HH * NN * DD;   // 3,145,728 elements
  const size_t NX = 3145728, NW = 1769472, NO = 589824;
  const size_t need = (4 * HD + NX + NW + NO) * sizeof(short)
                    + (size_t)2 * HH * DD * sizeof(float) + 64;
  if (ws_size < need) return;  // diagnostic: zero output

  short* Qb = (short*)d_ws;
  short* Kb = Qb + HD;
  short* VT = Kb + HD;
  short* AO = VT + HD;
  float* cs = (float*)(AO + HD);
  short* xb  = (short*)(cs + 2 * HH * DD);
  short* wqb = xb + NX;
  short* wob = wqb + NW;

  dim3 blk(256);
  norm_k<<<dim3(2688), blk, 0, stream>>>((const float*)d_in[0],
                                         (const float*)d_in[1],
                                         (const float*)d_in[2],
                                         xb, wqb, wob);
  gemm_k<0><<<dim3(2304 / 128, 4096 / 128), blk, 0, stream>>>(
      xb, wqb, nullptr, Qb, Kb, VT, nullptr);
  colsum_k<<<dim3(2 * HH), blk, 0, stream>>>(VT, cs);
  attn_k<<<dim3(24 * 32), dim3(128), 0, stream>>>(Qb, Kb, VT, cs, AO);
  gemm_k<1><<<dim3(CC / 128, 4096 / 128), blk, 0, stream>>>(
      AO, wob, (const float*)d_in[3], nullptr, nullptr, nullptr, out);
}

// Round 8
// 110.153 us; speedup vs baseline: 1.2088x; 1.1528x over previous
//
#include <hip/hip_runtime.h>
#include <hip/hip_bf16.h>
#include <cstdint>
#include <cstddef>

typedef __attribute__((ext_vector_type(8))) short short8;
typedef __attribute__((ext_vector_type(4))) short short4v;
typedef __attribute__((ext_vector_type(4))) float f32x4;
typedef __attribute__((ext_vector_type(16))) float f32x16;

#define HH 12
#define DD 64
#define NN 2048
#define CC 768
// 0.125 (HEAD_DIM^-0.5) * log2(e): lets attn use exp2 directly.
#define QSCALE 0.18033688011112042f

__device__ __forceinline__ float bf2f(short s) {
  union { uint32_t u; float f; } v;
  v.u = ((uint32_t)(uint16_t)s) << 16;
  return v.f;
}
__device__ __forceinline__ short f2bf(float f) {
  union { float f; uint32_t u; } v; v.f = f;
  uint32_t r = v.u + 0x7FFFu + ((v.u >> 16) & 1u);
  return (short)(r >> 16);
}
// packed f32x2 -> bf16x2 (low = a, high = b) in one instruction
__device__ __forceinline__ uint32_t cvtpk(float a, float b) {
  uint32_t r;
  asm("v_cvt_pk_bf16_f32 %0, %1, %2" : "=v"(r) : "v"(a), "v"(b));
  return r;
}

// ---------------------------------------------------------------------------
// Normalizer: fp32 -> bf16 for x, w_qkv, w_out.
// ---------------------------------------------------------------------------
__global__ __launch_bounds__(256)
void norm_k(const float* __restrict__ s0, const float* __restrict__ s1,
            const float* __restrict__ s2,
            short* __restrict__ d0, short* __restrict__ d1,
            short* __restrict__ d2)
{
  const int bid = blockIdx.x;
  const float* src; short* dst; int base;
  if (bid < 1536)      { src = s0; dst = d0; base = bid; }
  else if (bid < 2400) { src = s1; dst = d1; base = bid - 1536; }
  else                 { src = s2; dst = d2; base = bid - 2400; }
  const int idx = (base * 256 + (int)threadIdx.x) * 8;
  const float* sf = src + idx;
  f32x4 a = *(const f32x4*)sf;
  f32x4 b = *(const f32x4*)(sf + 4);
  short8 o;
  o[0] = f2bf(a[0]); o[1] = f2bf(a[1]); o[2] = f2bf(a[2]); o[3] = f2bf(a[3]);
  o[4] = f2bf(b[0]); o[5] = f2bf(b[1]); o[6] = f2bf(b[2]); o[7] = f2bf(b[3]);
  *(short8*)(dst + idx) = o;
}

// ---------------------------------------------------------------------------
// GEMM: C[m,f] = sum_c A[m,c] * W[f,c]   (A: [4096,768], W: [F,768], bf16)
// MODE 0: F=2304 -> Q (x QSCALE) [b,h,n,d], K [b,h,n,d], V^T [b,h,d,n]
// MODE 1: F=768 -> Of[m*768+f] = C + bias[f]  (fp32 out)
// ---------------------------------------------------------------------------
template <int MODE>
__global__ __launch_bounds__(256, 2)
void gemm_k(const short* __restrict__ A, const short* __restrict__ W,
            const float* __restrict__ bias,
            short* __restrict__ O0, short* __restrict__ O1, short* __restrict__ O2,
            float* __restrict__ Of)
{
  __shared__ __align__(16) short lA[128 * 64];
  __shared__ __align__(16) short lB[128 * 64];
  const int tid = threadIdx.x;
  const int w = tid >> 6, l = tid & 63;
  const int lq = l & 15, lh = l >> 4;
  const int m0 = blockIdx.y * 128;
  const int f0 = blockIdx.x * 128;
  const int seg = tid & 7;
  const int rbase = tid >> 3;

  f32x4 acc[4][4] = {};

  for (int kb = 0; kb < CC; kb += 64) {
    __syncthreads();
#pragma unroll
    for (int j = 0; j < 4; ++j) {
      const int row = j * 32 + rbase;
      const int dst = row * 128 + ((seg * 16) ^ ((row & 7) << 4));
      *(short8*)((char*)lA + dst) =
          *(const short8*)(A + (size_t)(m0 + row) * CC + kb + seg * 8);
      *(short8*)((char*)lB + dst) =
          *(const short8*)(W + (size_t)(f0 + row) * CC + kb + seg * 8);
    }
    __syncthreads();
    const int wr = (w >> 1) * 64, wc = (w & 1) * 64;
#pragma unroll
    for (int c = 0; c < 2; ++c) {
      short8 af[4], bfr[4];
#pragma unroll
      for (int i = 0; i < 4; ++i) {
        const int rowA = wr + i * 16 + lq;
        af[i] = *(const short8*)((char*)lA + rowA * 128 +
                                 ((c * 64 + lh * 16) ^ ((rowA & 7) << 4)));
        const int rowB = wc + i * 16 + lq;
        bfr[i] = *(const short8*)((char*)lB + rowB * 128 +
                                  ((c * 64 + lh * 16) ^ ((rowB & 7) << 4)));
      }
#pragma unroll
      for (int mi = 0; mi < 4; ++mi)
#pragma unroll
        for (int ni = 0; ni < 4; ++ni)
          acc[mi][ni] = __builtin_amdgcn_mfma_f32_16x16x32_bf16(
              af[mi], bfr[ni], acc[mi][ni], 0, 0, 0);
    }
  }

  const int wr = (w >> 1) * 64, wc = (w & 1) * 64;
#pragma unroll
  for (int ni = 0; ni < 4; ++ni) {
    const int fb = f0 + wc + ni * 16;
    if (MODE == 0) {
      const int which = fb / CC;          // uniform per fragment
      const int hd = fb - which * CC;
      const int h = hd >> 6;              // uniform
      const int d = (hd & 63) + lq;
#pragma unroll
      for (int mi = 0; mi < 4; ++mi) {
        const int mb = m0 + wr + mi * 16 + 4 * lh;
        const int b = mb >> 11;
        const int n = mb & 2047;
        if (which == 0) {
#pragma unroll
          for (int r = 0; r < 4; ++r)
            O0[(((size_t)(b * HH + h) * NN) + n + r) * DD + d] =
                f2bf(acc[mi][ni][r] * QSCALE);
        } else if (which == 1) {
#pragma unroll
          for (int r = 0; r < 4; ++r)
            O1[(((size_t)(b * HH + h) * NN) + n + r) * DD + d] =
                f2bf(acc[mi][ni][r]);
        } else {
          short4v pk;
#pragma unroll
          for (int r = 0; r < 4; ++r) pk[r] = f2bf(acc[mi][ni][r]);
          *(short4v*)(O2 + ((size_t)(b * HH + h) * DD + d) * NN + n) = pk;
        }
      }
    } else {
      const float bv = bias[fb + lq];
#pragma unroll
      for (int mi = 0; mi < 4; ++mi) {
        const int mb = m0 + wr + mi * 16 + 4 * lh;
#pragma unroll
        for (int r = 0; r < 4; ++r)
          Of[(size_t)(mb + r) * CC + fb + lq] = acc[mi][ni][r] + bv;
      }
    }
  }
}

// ---------------------------------------------------------------------------
// colsumV[bh,d] = sum_n V[bh,n,d]  (from V^T [bh,d,n])
// ---------------------------------------------------------------------------
__global__ __launch_bounds__(256)
void colsum_k(const short* __restrict__ VT, float* __restrict__ cs)
{
  const int bh = blockIdx.x, t = threadIdx.x;
  const int d = t >> 2, part = t & 3;
  const short* p = VT + ((size_t)bh * DD + d) * NN + part * 512;
  float s = 0.f;
  for (int i = 0; i < 512; i += 8) {
    short8 v = *(const short8*)(p + i);
#pragma unroll
    for (int e = 0; e < 8; ++e) s += bf2f(v[e]);
  }
  s += __shfl_xor(s, 1);
  s += __shfl_xor(s, 2);
  if (part == 0) cs[bh * DD + d] = s;
}

// ---------------------------------------------------------------------------
// Attention: 768 blocks x 256 thr.  4 waves = 2 q-subtiles x 2 k-chunks.
// Each k-chunk pair stages its own 64-key K/V tile (16 KB), sweeps 1024 keys.
// Intra-block split-K combine through a 17 KB LDS overlay -> no HBM partials.
// 32x32x16 MFMA, swapped QK^T (lane owns q=lane&31); P->A-frag via
// v_permlane32_swap_b32.  Linearized 2nd softmax:
//   out = (csV*l1 + P1) / (2048*l1 + s1),  s1 = l1 - 0.5*mc.
// ---------------------------------------------------------------------------
__global__ __launch_bounds__(256, 3)
void attn_k(const short* __restrict__ Qb, const short* __restrict__ Kb,
            const short* __restrict__ VT, const float* __restrict__ cs,
            short* __restrict__ AO)
{
  __shared__ __align__(16) char smem[32768];   // staging; combine overlay
  float* comb  = (float*)smem;                 // [64 q][64 d] fp32
  float* combL = comb + 4096;                  // l1 partials [64]
  float* combM = comb + 4160;                  // mc partials [64]

  const int tid = threadIdx.x;
  const int w = tid >> 6, l = tid & 63;
  const int lq = l & 31, hi = l >> 5;
  const int qp = w & 1;                        // q subtile (0: q0-31, 1: q32-63)
  const int kc = w >> 1;                       // k chunk   (0: k<1024, 1: k>=1024)

  // XCD-aware chunked swizzle: 768 % 8 == 0, bijective.
  const int bid = (int)blockIdx.x;
  const int sbid = (bid & 7) * 96 + (bid >> 3);
  const int bh = sbid >> 5;
  const int qblk = sbid & 31;

  const short* Qh = Qb + (size_t)bh * NN * DD;
  const short* Kh = Kb + (size_t)bh * NN * DD;
  const short* Vh = VT + (size_t)bh * DD * NN;

  const int qw = qblk * 64 + qp * 32;
  const int qg = qw + lq;

  // B-frag of Q: rows d = c*16 + hi*8 + 0..7, col q = lq
  short8 qf[4];
#pragma unroll
  for (int c = 0; c < 4; ++c)
    qf[c] = *(const short8*)(Qh + (size_t)qg * DD + c * 16 + hi * 8);

  f32x16 pv[2] = {};
  float l1x[4] = {};
  float mc = 0.f;

  // staging: the 128 threads of each k-chunk pair stage their own tile
  const int lt = tid & 127;
  const int seg = lt & 7, rbase = lt >> 3;     // 8 segs x 16 rows
  const int cbase = kc * 16384;                // this chunk's staging base (bytes)
  int sdstK[4], sdstV[4], ksrc[4], vsrc[4];
#pragma unroll
  for (int j = 0; j < 4; ++j) {
    const int row = j * 16 + rbase;
    const int sw = row * 128 + ((seg * 16) ^ ((row & 7) << 4));
    sdstK[j] = cbase + sw;
    sdstV[j] = cbase + 8192 + sw;
    ksrc[j] = row * DD + seg * 8;
    vsrc[j] = row * NN + seg * 8;
  }
  // hoisted LDS frag-read addresses (loop-invariant)
  int kaddr[8], vaddr[8];
#pragma unroll
  for (int kg = 0; kg < 2; ++kg) {
    const int rowK = kg * 32 + lq;
#pragma unroll
    for (int c = 0; c < 4; ++c)
      kaddr[kg * 4 + c] =
          cbase + rowK * 128 + ((c * 32 + hi * 16) ^ ((rowK & 7) << 4));
  }
#pragma unroll
  for (int dg = 0; dg < 2; ++dg) {
    const int rowV = dg * 32 + lq;
#pragma unroll
    for (int ch = 0; ch < 4; ++ch)
      vaddr[ch * 2 + dg] =
          cbase + 8192 + rowV * 128 + ((ch * 32 + hi * 16) ^ ((rowV & 7) << 4));
  }

  const int kb0 = kc * (NN / 2);
  for (int t = 0; t < NN / 2; t += 64) {
    const int kb = kb0 + t;
    __syncthreads();
#pragma unroll
    for (int j = 0; j < 4; ++j) {
      *(short8*)(smem + sdstK[j]) = *(const short8*)(Kh + (size_t)kb * DD + ksrc[j]);
      *(short8*)(smem + sdstV[j]) = *(const short8*)(Vh + kb + vsrc[j]);
    }
    __syncthreads();

    // QK^T: sacc[kg] = S[key = kb + kg*32 + crow, q = qg] * log2e
    // crow = (reg&3) + 8*(reg>>2) + 4*hi
    f32x16 sacc[2] = {};
#pragma unroll
    for (int kg = 0; kg < 2; ++kg)
#pragma unroll
      for (int c = 0; c < 4; ++c) {
        short8 kf = *(const short8*)(smem + kaddr[kg * 4 + c]);
        sacc[kg] = __builtin_amdgcn_mfma_f32_32x32x16_bf16(kf, qf[c], sacc[kg], 0, 0, 0);
      }

    // elementwise: e = exp2(s); mask hoisted to rare wave-uniform tiles
    uint32_t dwv[2][8];
    const int u = (qw - kb) & 511;
    if (u < 64 || u > 480) {
      const int delta = (qg - kb) & 511;
      int mreg = -1;
      if (delta < 64 && (((delta >> 2) & 1) == hi))
        mreg = (delta >> 5) * 16 + (delta & 3) + (((delta & 31) >> 3) << 2);
#pragma unroll
      for (int kg = 0; kg < 2; ++kg) {
        float uv[16];
#pragma unroll
        for (int r = 0; r < 16; ++r) {
          float e = __builtin_exp2f(sacc[kg][r]);
          l1x[r & 3] += e;
          const bool m = (kg * 16 + r) == mreg;
          mc += m ? e : 0.f;
          uv[r] = m ? 0.5f * e : e;
        }
#pragma unroll
        for (int j2 = 0; j2 < 8; ++j2)
          dwv[kg][j2] = cvtpk(uv[2 * j2], uv[2 * j2 + 1]);
      }
    } else {
#pragma unroll
      for (int kg = 0; kg < 2; ++kg) {
        float uv[16];
#pragma unroll
        for (int r = 0; r < 16; ++r) {
          const float e = __builtin_exp2f(sacc[kg][r]);
          l1x[r & 3] += e;
          uv[r] = e;
        }
#pragma unroll
        for (int j2 = 0; j2 < 8; ++j2)
          dwv[kg][j2] = cvtpk(uv[2 * j2], uv[2 * j2 + 1]);
      }
    }

    // Build PV A-frags (P[q][k], row=q=lq, cols k = ch*16 + hi*8 + 0..7)
    short8 pa[4];
#pragma unroll
    for (int kg = 0; kg < 2; ++kg)
#pragma unroll
      for (int half = 0; half < 2; ++half) {
        uint32_t a0 = dwv[kg][4 * half + 0], a1 = dwv[kg][4 * half + 1];
        uint32_t a2 = dwv[kg][4 * half + 2], a3 = dwv[kg][4 * half + 3];
        asm("v_permlane32_swap_b32 %0, %1" : "+v"(a0), "+v"(a2));
        asm("v_permlane32_swap_b32 %0, %1" : "+v"(a1), "+v"(a3));
        union { uint32_t u4[4]; short8 s; } pk;
        pk.u4[0] = a0; pk.u4[1] = a1; pk.u4[2] = a2; pk.u4[3] = a3;
        pa[kg * 2 + half] = pk.s;
      }

    // PV: pv[dg][reg] = O[q = crow, d = dg*32 + lq]
#pragma unroll
    for (int ch = 0; ch < 4; ++ch)
#pragma unroll
      for (int dg = 0; dg < 2; ++dg) {
        short8 vf = *(const short8*)(smem + vaddr[ch * 2 + dg]);
        pv[dg] = __builtin_amdgcn_mfma_f32_32x32x16_bf16(pa[ch], vf, pv[dg], 0, 0, 0);
      }
  }

  // per-chunk l1, mc for q = qw + lq (keys split across lane halves)
  float l1 = (l1x[0] + l1x[1]) + (l1x[2] + l1x[3]);
  l1 += __shfl_xor(l1, 32);
  mc += __shfl_xor(mc, 32);

  // ---- intra-block split-K combine via LDS overlay ----
  __syncthreads();                    // all staging reads done; safe to overlay
  if (kc == 1) {
#pragma unroll
    for (int dg = 0; dg < 2; ++dg)
#pragma unroll
      for (int r = 0; r < 16; ++r) {
        const int qrow = (r & 3) + 8 * (r >> 2) + 4 * hi;
        comb[(qp * 32 + qrow) * 64 + dg * 32 + lq] = pv[dg][r];
      }
    if (hi == 0) {
      combL[qp * 32 + lq] = l1;
      combM[qp * 32 + lq] = mc;
    }
  }
  __syncthreads();
  if (kc == 0) {
    const float l1t = l1 + combL[qp * 32 + lq];
    const float mct = mc + combM[qp * 32 + lq];
    const float s1t = l1t - 0.5f * mct;
    const int b = bh / HH, h = bh - b * HH;
#pragma unroll
    for (int r = 0; r < 16; ++r) {
      const int qrow = (r & 3) + 8 * (r >> 2) + 4 * hi;
      const float l1r = __shfl(l1t, qrow);
      const float s1r = __shfl(s1t, qrow);
      const float rden = 1.f / (2048.f * l1r + s1r);
      const int n = qw + qrow;
#pragma unroll
      for (int dg = 0; dg < 2; ++dg) {
        const int d = dg * 32 + lq;
        const float pvt = pv[dg][r] + comb[(qp * 32 + qrow) * 64 + d];
        const float csv = cs[bh * DD + d];
        AO[((size_t)(b * NN + n)) * CC + h * DD + d] =
            f2bf((csv * l1r + pvt) * rden);
      }
    }
  }
}

// ---------------------------------------------------------------------------
extern "C" void kernel_launch(void* const* d_in, const int* in_sizes, int n_in,
                              void* d_out, int out_size, void* d_ws, size_t ws_size,
                              hipStream_t stream)
{
  (void)in_sizes; (void)n_in; (void)out_size;
  float* out = (float*)d_out;

  const size_t HD = (size_t)2 * HH * NN * DD;   // 3,145,728 elements
  const size_t NX = 3145728, NW = 1769472, NO = 589824;
  const size_t need = (4 * HD + NX + NW + NO) * sizeof(short)
                    + (size_t)2 * HH * DD * sizeof(float) + 64;
  if (ws_size < need) return;  // diagnostic: zero output

  short* Qb = (short*)d_ws;
  short* Kb = Qb + HD;
  short* VT = Kb + HD;
  short* AO = VT + HD;
  float* cs = (float*)(AO + HD);
  short* xb  = (short*)(cs + 2 * HH * DD);
  short* wqb = xb + NX;
  short* wob = wqb + NW;

  dim3 blk(256);
  norm_k<<<dim3(2688), blk, 0, stream>>>((const float*)d_in[0],
                                         (const float*)d_in[1],
                                         (const float*)d_in[2],
                                         xb, wqb, wob);
  gemm_k<0><<<dim3(2304 / 128, 4096 / 128), blk, 0, stream>>>(
      xb, wqb, nullptr, Qb, Kb, VT, nullptr);
  colsum_k<<<dim3(2 * HH), blk, 0, stream>>>(VT, cs);
  attn_k<<<dim3(24 * 32), blk, 0, stream>>>(Qb, Kb, VT, cs, AO);
  gemm_k<1><<<dim3(CC / 128, 4096 / 128), blk, 0, stream>>>(
      AO, wob, (const float*)d_in[3], nullptr, nullptr, nullptr, out);
}